// Round 12
// baseline (51.673 us; speedup 1.0000x reference)
//
#include <hip/hip_runtime.h>
#include <cstdint>
#include <cstddef>

#define NEG_SLOPE 0.2f
#define LOG2E 1.4426950408889634f

// Problem sizes (fixed by setup_inputs)
#define BB 2
#define NN 2048
#define DD 512
#define HH 8
#define KK 64   // head dim

typedef _Float16 half8 __attribute__((ext_vector_type(8)));
typedef _Float16 half4 __attribute__((ext_vector_type(4)));
typedef _Float16 half2v __attribute__((ext_vector_type(2)));
typedef float floatx4 __attribute__((ext_vector_type(4)));

// Workspace layout (bytes)
#define X16T_OFF  ((size_t)0)            // x16 tiled: [256 mtile][64 chunk][16 m][8 k] f16 = 4 MB
#define WT_OFF    ((size_t)4194304)      // WT[o][d] f16 = 512 KB
#define XHT_OFF   ((size_t)4718592)      // xhT2: [B*H][32 c][64 kk][64 j] f16 (pre-swizzled) = 4 MB
#define ASRC_OFF  ((size_t)8912896)      // 32768 f32 = 128 KB
#define AFP_OFF   ((size_t)9043968)      // aFp: [bh][n/2] u32 (F+ pairs) = 64 KB
#define AFM_OFF   ((size_t)9109504)      // aFm: [bh][n/2] u32 (F- pairs) = 64 KB
#define ADMAX_OFF ((size_t)9175040)      // [16 bh][128] f32 = 8 KB
#define MW_OFF    ((size_t)9183232)      // mwT: [B][32][2048] u64 = 1 MB

// async global->LDS, 16B per lane; lbase is wave-uniform, lane writes lbase+lane*16
#if __has_builtin(__builtin_amdgcn_global_load_lds)
#define GLL(gsrc, lbase, lane) \
    __builtin_amdgcn_global_load_lds((const __attribute__((address_space(1))) void*)(gsrc), \
                                     (__attribute__((address_space(3))) void*)(lbase), 16, 0, 0)
#else
#define GLL(gsrc, lbase, lane) \
    (*(uint4*)((char*)(lbase) + (size_t)(lane) * 16) = *(const uint4*)(gsrc))
#endif

// packed pair op: max(Ep2*fp, Em2*fm) elementwise on 2 f16 halves
// clang vector ops: * -> v_pk_mul_f16, __builtin_elementwise_max -> v_pk_max_f16
__device__ __forceinline__ unsigned pkmm(unsigned Ep2, unsigned fp,
                                         unsigned Em2, unsigned fm) {
    union U { unsigned u; half2v h; };
    U a, b, c, d, r;
    a.u = Ep2; b.u = fp; c.u = Em2; d.u = fm;
    r.h = __builtin_elementwise_max(a.h * b.h, c.h * d.h);
    return r.u;
}

// ---------------- Kernel 0: x->f16 tiled + W transpose->f16 -------------------
__global__ __launch_bounds__(256) void k_prep(const float* __restrict__ x,
                                              const float* __restrict__ Wp,
                                              _Float16* __restrict__ x16t,
                                              _Float16* __restrict__ WT) {
    __shared__ float tile[64][65];
    const int tid = threadIdx.x;
    const int bi = blockIdx.x;
    if (bi < 256) {                       // x conversion to tiled layout
        const int r = tid & 15, cg = tid >> 4;
        const float* srow = x + (size_t)(bi * 16 + r) * DD;
        _Float16* obase = x16t + ((size_t)bi * 64) * 128 + r * 8;
#pragma unroll
        for (int q = 0; q < 4; ++q) {
            const int chunk = q * 16 + cg;
            float4 v0 = *(const float4*)(srow + chunk * 8);
            float4 v1 = *(const float4*)(srow + chunk * 8 + 4);
            half8 hv;
            hv[0] = (_Float16)v0.x; hv[1] = (_Float16)v0.y;
            hv[2] = (_Float16)v0.z; hv[3] = (_Float16)v0.w;
            hv[4] = (_Float16)v1.x; hv[5] = (_Float16)v1.y;
            hv[6] = (_Float16)v1.z; hv[7] = (_Float16)v1.w;
            *(half8*)(obase + (size_t)chunk * 128) = hv;
        }
    } else {                              // W transpose: 64 blocks of 64x64
        const int wb = bi - 256;
        const int d0 = (wb >> 3) * 64, o0 = (wb & 7) * 64;
        const int r = tid >> 2, cq = tid & 3;
#pragma unroll
        for (int qq = 0; qq < 4; ++qq) {
            float4 v = *(const float4*)&Wp[(size_t)(d0 + r) * DD + o0 + cq * 16 + qq * 4];
            tile[r][cq * 16 + qq * 4 + 0] = v.x;
            tile[r][cq * 16 + qq * 4 + 1] = v.y;
            tile[r][cq * 16 + qq * 4 + 2] = v.z;
            tile[r][cq * 16 + qq * 4 + 3] = v.w;
        }
        __syncthreads();
#pragma unroll
        for (int qq = 0; qq < 2; ++qq) {
            half8 hv;
#pragma unroll
            for (int e = 0; e < 8; ++e) hv[e] = (_Float16)tile[cq * 16 + qq * 8 + e][r];
            *(half8*)&WT[(size_t)(o0 + r) * DD + d0 + cq * 16 + qq * 8] = hv;
        }
    }
}

// ---------------- Kernel 1: FUSED mask pack (1024 blk) + proj GEMM (512 blk) --
// bi%3 interleave co-schedules HBM-streaming mask blocks with compute-bound
// proj blocks (overlap, one less launch). Mask body identical to proven R7 form.
__global__ __launch_bounds__(256) void k_pj(const int* __restrict__ A,
                                            const _Float16* __restrict__ x16t,
                                            const _Float16* __restrict__ WT,
                                            const float* __restrict__ Watt,
                                            unsigned long long* __restrict__ mwT,
                                            _Float16* __restrict__ xhT2,
                                            float* __restrict__ asrc,
                                            unsigned* __restrict__ aFp_g,
                                            unsigned* __restrict__ aFm_g,
                                            float* __restrict__ admax) {
    __shared__ __align__(16) char smem[65536];        // proj B-tile / mask scratch
    const int tid = threadIdx.x;
    const int bi = blockIdx.x;
    const int r3 = bi % 3;

    if (r3 != 2) {                        // ---- mask pack, transposed [b][c][n]
        unsigned long long (*mwt)[4] = (unsigned long long (*)[4])smem;
        const int mid = (bi / 3) * 2 + r3;             // 0..1023
        const int w = tid >> 6, lane = tid & 63;
        const int b = mid >> 9, n0 = (mid & 511) * 4;
        const int* Arow = A + ((size_t)b * NN + n0 + w) * NN + lane;
        int v[32];
#pragma unroll
        for (int c = 0; c < 32; ++c) v[c] = Arow[c * 64];
#pragma unroll
        for (int c = 0; c < 32; ++c) {
            unsigned long long m = __ballot(v[c] != 0);
            if (lane == 0) mwt[c][w] = m;
        }
        __syncthreads();
        if (tid < 128) {
            const int c = tid >> 2, rl = tid & 3;
            mwT[((size_t)b * 32 + c) * NN + n0 + rl] = mwt[c][rl];
        }
        return;
    }

    // ---- proj GEMM block
    _Float16* bt = (_Float16*)smem;                    // 64 KB B tile
    const int pid = bi / 3;                            // 0..511
    const int mtile = pid >> 3, h = pid & 7;
    const int m0 = mtile * 64;
    // stage B: row = q*4 + wave, 1KB per row, chunk XOR (row&7)
    {
        const int cir = tid & 63, wv4 = tid >> 6;
        const char* gsrc = (const char*)(WT + (size_t)h * 64 * DD);
        char* lbase = (char*)bt;
#pragma unroll
        for (int q = 0; q < 16; ++q) {
            const int row = q * 4 + wv4;
            *(uint4*)(lbase + row * 1024 + ((cir ^ (row & 7)) * 16)) =
                *(const uint4*)(gsrc + (size_t)row * 1024 + cir * 16);
        }
    }
    __syncthreads();
    const int w = tid >> 6, l = tid & 63, li = l & 15, p = l >> 4;
    const char* bbase = (const char*)bt;
    const _Float16* abase = x16t + ((size_t)(mtile * 4 + w)) * 64 * 128 + li * 8;
    floatx4 acc[4] = {};
    for (int k0 = 0; k0 < DD; k0 += 32) {
        const int ch = (k0 >> 3) + p;
        half8 a = *(const half8*)(abase + (size_t)ch * 128);
#pragma unroll
        for (int ct = 0; ct < 4; ++ct) {
            const int row = ct * 16 + li;
            half8 bfr = *(const half8*)(bbase + row * 1024 + ((ch ^ (li & 7)) * 16));
            acc[ct] = __builtin_amdgcn_mfma_f32_16x16x32_f16(a, bfr, acc[ct], 0, 0, 0);
        }
    }
    const int b = m0 >> 11, n0m = m0 & (NN - 1);
    const int c = n0m >> 6;
    const int bh = b * HH + h;
    // xhT2 tile write, swizzle baked in
    {
        char* tb2 = (char*)xhT2 + ((size_t)(bh * 32 + c)) * 8192;
        const int colchunk = w * 2 + (p >> 1);
        const int sub = (p & 1) * 8;
#pragma unroll
        for (int ct = 0; ct < 4; ++ct) {
            const int kk = ct * 16 + li;
            half4 hv;
#pragma unroll
            for (int r = 0; r < 4; ++r) hv[r] = (_Float16)acc[ct][r];
            *(half4*)(tb2 + kk * 128 + ((colchunk ^ (kk & 7)) << 4) + sub) = hv;
        }
    }
    // fused a_src / packed F-pairs + per-wave adst max partial
    float w1[4], w2[4];
#pragma unroll
    for (int ct = 0; ct < 4; ++ct) {
        w1[ct] = Watt[h * 128 + ct * 16 + li];
        w2[ct] = Watt[h * 128 + 64 + ct * 16 + li];
    }
    float s1v[4], s2v[4];
    float mx = -1e30f;
#pragma unroll
    for (int r = 0; r < 4; ++r) {
        float s1 = 0.f, s2 = 0.f;
#pragma unroll
        for (int ct = 0; ct < 4; ++ct) { s1 += acc[ct][r] * w1[ct]; s2 += acc[ct][r] * w2[ct]; }
#pragma unroll
        for (int d = 1; d < 16; d <<= 1) { s1 += __shfl_xor(s1, d, 64); s2 += __shfl_xor(s2, d, 64); }
        s1v[r] = s1; s2v[r] = s2;
        mx = fmaxf(mx, s2);
    }
    mx = fmaxf(mx, __shfl_xor(mx, 16, 64));
    mx = fmaxf(mx, __shfl_xor(mx, 32, 64));
    if (l == 0) admax[bh * 128 + (mtile & 31) * 4 + w] = mx;
    if (li == 0) {
        const int nb = n0m + w * 16 + p * 4;
        *(float4*)&asrc[bh * NN + nb] = make_float4(s1v[0], s1v[1], s1v[2], s1v[3]);
        union { half2v h; unsigned u; } q;
        unsigned fpw[2], fmw[2];
#pragma unroll
        for (int pr = 0; pr < 2; ++pr) {
            q.h[0] = (_Float16)exp2f(s2v[2 * pr] * LOG2E);
            q.h[1] = (_Float16)exp2f(s2v[2 * pr + 1] * LOG2E);
            fpw[pr] = q.u;
            q.h[0] = (_Float16)exp2f(NEG_SLOPE * s2v[2 * pr] * LOG2E);
            q.h[1] = (_Float16)exp2f(NEG_SLOPE * s2v[2 * pr + 1] * LOG2E);
            fmw[pr] = q.u;
        }
        const int wb = (bh * NN + nb) >> 1;
        *(uint2*)&aFp_g[wb] = make_uint2(fpw[0], fpw[1]);
        *(uint2*)&aFm_g[wb] = make_uint2(fmw[0], fmw[1]);
    }
}

// ---------------- Kernel 2: masked softmax + PV via MFMA (R8 geometry) --------
// 256 thr / 4 waves, 32-row i-tile, grid 1024 (4 blk/CU). Wave: g=w&1 parity,
// wr=w>>1 row-half. V tiles double-buffered via global_load_lds. Scores built
// pairwise-packed: af word = max(Ep2*Fp, Em2*Fm) & maskword  (v_pk path).
__global__ __launch_bounds__(256) void k_attn(const _Float16* __restrict__ xhT2,
                                              const float* __restrict__ asrc,
                                              const unsigned* __restrict__ aFp,
                                              const unsigned* __restrict__ aFm,
                                              const float* __restrict__ admax,
                                              const unsigned long long* __restrict__ mwT,
                                              const float* __restrict__ batt,
                                              float* __restrict__ out) {
    __shared__ __align__(16) _Float16 vt[2][2][4096];     // [parity][buf][8KB]
    __shared__ __align__(16) unsigned aFpl[2][2][32];     // F+ pairs
    __shared__ __align__(16) unsigned aFml[2][2][32];     // F- pairs
    __shared__ unsigned long long mwl[2][2][32];
    __shared__ float accd_s[2][16];
    __shared__ float amx_s;

    const int tid = threadIdx.x;
    const int w = tid >> 6, l = tid & 63, li = l & 15, p = l >> 4;
    const int g = w & 1, wr = w >> 1;
    const int bid = blockIdx.x;
    const int bh = bid >> 6, it = bid & 63;
    const int b = bh >> 3, h = bh & (HH - 1);
    const int i0 = it * 32;

    const _Float16* vbase = xhT2 + (size_t)bh * 32 * 4096;  // tile = 4096 halves

    // ---- prologue: stage tile pair ci=0 (c = parity) into buf 0
    {
#pragma unroll
        for (int q = 0; q < 4; ++q) {
            const int chunk = (wr * 4 + q) * 64 + l;       // 16B chunk index in tile
            GLL(vbase + (size_t)g * 4096 + chunk * 8, &vt[g][0][(wr * 4 + q) * 512], l);
        }
        if (tid < 128) {
            const int arr = tid >> 6, par = (tid >> 5) & 1, wd = tid & 31;
            const unsigned v = (arr ? aFm : aFp)[bh * 1024 + par * 32 + wd];
            if (arr) aFml[par][0][wd] = v; else aFpl[par][0][wd] = v;
        }
        if (tid < 64) mwl[tid >> 5][0][tid & 31] =
            mwT[((size_t)b * 32 + (tid >> 5)) * NN + i0 + (tid & 31)];
    }
    // reduce 128 adst-max partials (wave 0)
    if (w == 0) {
        float mx = fmaxf(admax[bh * 128 + l], admax[bh * 128 + 64 + l]);
#pragma unroll
        for (int d = 1; d < 64; d <<= 1) mx = fmaxf(mx, __shfl_xor(mx, d, 64));
        if (l == 0) amx_s = mx;
    }
    __syncthreads();   // drains GLL (vmcnt) + LDS writes; amx_s visible

    const float am = amx_s;
    const float bbv = batt[h];
    const int i = i0 + wr * 16 + li;
    const float ai = (asrc[bh * NN + i] + bbv) * LOG2E;    // log2-domain src score
    const float tb = ai + am * LOG2E;
    const float Mi = fmaxf(tb, NEG_SLOPE * tb);            // row-max upper bound
    union { half2v h; unsigned u; } epk, emk;
    epk.h[0] = epk.h[1] = (_Float16)exp2f(ai - Mi);        // E+ broadcast pair
    emk.h[0] = emk.h[1] = (_Float16)exp2f(NEG_SLOPE * ai - Mi);  // E- broadcast
    const unsigned Ep2 = epk.u, Em2 = emk.u;
    floatx4 acc[4] = {};
    floatx4 accd = {};
    half8 ones;
#pragma unroll
    for (int e = 0; e < 8; ++e) ones[e] = (_Float16)1.0f;

    unsigned raf = 0; unsigned long long rmw = 0;
    for (int ci = 0; ci < 16; ++ci) {
        const int buf = ci & 1;
        char* vtg = (char*)&vt[g][buf][0];
        // issue next tile's loads (fly during compute below)
        if (ci < 15) {
            const int cb = 2 * (ci + 1);
            const int cn = cb + g;
#pragma unroll
            for (int q = 0; q < 4; ++q) {
                const int chunk = (wr * 4 + q) * 64 + l;
                GLL(vbase + (size_t)cn * 4096 + chunk * 8, &vt[g][buf ^ 1][(wr * 4 + q) * 512], l);
            }
            if (tid < 128) {
                const int arr = tid >> 6, par = (tid >> 5) & 1, wd = tid & 31;
                raf = (arr ? aFm : aFp)[bh * 1024 + (cb + par) * 32 + wd];
            }
            if (tid < 64) rmw = mwT[((size_t)b * 32 + cb + (tid >> 5)) * NN + i0 + (tid & 31)];
        }
        // compute current tile
        const unsigned long long mword = mwl[g][buf][wr * 16 + li];
#pragma unroll
        for (int js = 0; js < 2; ++js) {
            const int wb = js * 16 + p * 4;
            const uint4 Fp4 = *(const uint4*)&aFpl[g][buf][wb];
            const uint4 Fm4 = *(const uint4*)&aFml[g][buf][wb];
            const unsigned m8 = (unsigned)(mword >> (js * 32 + p * 8)) & 0xFFu;
            const unsigned fpv[4] = {Fp4.x, Fp4.y, Fp4.z, Fp4.w};
            const unsigned fmv[4] = {Fm4.x, Fm4.y, Fm4.z, Fm4.w};
            union { unsigned u[4]; half8 h; } afu;
#pragma unroll
            for (int pi = 0; pi < 4; ++pi) {
                const unsigned m2 = (m8 >> (2 * pi)) & 3u;
                const unsigned mk = ((m2 & 1u) ? 0x0000FFFFu : 0u) |
                                    ((m2 & 2u) ? 0xFFFF0000u : 0u);
                afu.u[pi] = pkmm(Ep2, fpv[pi], Em2, fmv[pi]) & mk;
            }
            const half8 af = afu.h;
            accd = __builtin_amdgcn_mfma_f32_16x16x32_f16(af, ones, accd, 0, 0, 0);
#pragma unroll
            for (int ct = 0; ct < 4; ++ct) {
                const half8 bf = *(const half8*)(vtg + (ct * 16 + li) * 128 +
                                                 (((js * 4 + p) ^ (li & 7)) << 4));
                acc[ct] = __builtin_amdgcn_mfma_f32_16x16x32_f16(af, bf, acc[ct], 0, 0, 0);
            }
        }
        // commit next tile's small state, then single barrier
        if (ci < 15) {
            if (tid < 128) {
                const int arr = tid >> 6, par = (tid >> 5) & 1, wd = tid & 31;
                if (arr) aFml[par][buf ^ 1][wd] = raf; else aFpl[par][buf ^ 1][wd] = raf;
            }
            if (tid < 64) mwl[tid >> 5][buf ^ 1][tid & 31] = rmw;
        }
        __syncthreads();
    }

    // combine the two c-parities (pair = waves with same wr) via LDS
    float* accs = (float*)&vt[0][0][0];    // 8 KB: [32 rows][64 cols]
    if (g == 1) {
#pragma unroll
        for (int ct = 0; ct < 4; ++ct)
#pragma unroll
            for (int r = 0; r < 4; ++r)
                accs[(wr * 16 + p * 4 + r) * 64 + ct * 16 + li] = acc[ct][r];
        if (li == 0) {
#pragma unroll
            for (int r = 0; r < 4; ++r) accd_s[wr][p * 4 + r] = accd[r];
        }
    }
    __syncthreads();
    if (g == 0) {
#pragma unroll
        for (int r = 0; r < 4; ++r) {
            const float d = accd[r] + accd_s[wr][p * 4 + r];
            const float inv = 1.f / fmaxf(d, 1e-30f);
            const int irow = i0 + wr * 16 + p * 4 + r;
            float* orow = out + ((size_t)b * NN + irow) * DD + h * KK;
#pragma unroll
            for (int ct = 0; ct < 4; ++ct) {
                const float v = (acc[ct][r] + accs[(wr * 16 + p * 4 + r) * 64 + ct * 16 + li]) * inv;
                orow[ct * 16 + li] = fmaxf(v, 0.f);
            }
        }
    }
}

extern "C" void kernel_launch(void* const* d_in, const int* in_sizes, int n_in,
                              void* d_out, int out_size, void* d_ws, size_t ws_size,
                              hipStream_t stream) {
    const float* x    = (const float*)d_in[0];
    const int*   A    = (const int*)d_in[1];
    const float* Wp   = (const float*)d_in[2];
    const float* Watt = (const float*)d_in[3];
    const float* batt = (const float*)d_in[4];
    float* out = (float*)d_out;

    char* ws = (char*)d_ws;
    _Float16* x16t = (_Float16*)(ws + X16T_OFF);
    _Float16* WT   = (_Float16*)(ws + WT_OFF);
    _Float16* xhT2 = (_Float16*)(ws + XHT_OFF);
    float* asrc  = (float*)(ws + ASRC_OFF);
    unsigned* aFp = (unsigned*)(ws + AFP_OFF);
    unsigned* aFm = (unsigned*)(ws + AFM_OFF);
    float* admax = (float*)(ws + ADMAX_OFF);
    unsigned long long* mwT = (unsigned long long*)(ws + MW_OFF);

    k_prep<<<dim3(320), 256, 0, stream>>>(x, Wp, x16t, WT);
    k_pj<<<dim3(1536), 256, 0, stream>>>(A, x16t, WT, Watt, mwT, xhT2, asrc, aFp, aFm, admax);
    k_attn<<<dim3(BB * HH * 64), 256, 0, stream>>>(xhT2, asrc, aFp, aFm, admax, mwT, batt, out);
}